// Round 5
// baseline (462.669 us; speedup 1.0000x reference)
//
#include <hip/hip_runtime.h>
#include <hip/hip_bf16.h>

// N=4, T=8 -> NT=32 batches; C=C2=256; H*W=1024.
// ONE kernel. Block = (nt, 64-q strip), 512 threads (8 waves), all 512
// blocks co-resident (2/CU).
//
// Key identity: pval[c,q] = sum_p V[c,p]*attn[p,q] = inv[q] * sum_p V*e.
// So PV consumes RAW e and needs no colsum until its epilogue -> PV fuses
// into the scores pass, fed from the accumulator REGISTERS through LDS
// (no global e consumption in the MFMA pipeline at all).
//
// Per p-tile of 256 (x4):
//   S0..S3: scores MFMA (Q resident in LDS, K 64-c chunks via reg prefetch)
//   epilogue: e = exp(s/16) in-place in acc; colsum partials; raw-e f32
//             store to the attn slot (scratch until tail; fire-and-forget)
//   P0..P3: PV sub-chunks of 64 p: Vs staged by all waves (reg-prefetched),
//           Ps[q][p] staged by the 2 waves holding that p-range (pk2 of
//           adjacent-row pairs from acc), 8 MFMAs/wave into av (raw V*e).
// Tail: colsum LDS-reduce -> inv; pval = av*inv; then a BARRIER-FREE
//       streaming normalize of the block's own attn strip (read raw e,
//       *inv, write back in place; L2/L3-hot).
// K/V prefetch time-share ONE 32-VGPR block (pf) to keep VGPR<=128
// (16 waves/CU). lgkm-only barriers keep prefetch loads in flight.
// d_out = [ p_val : 32*256*1024 f32 ][ attn : 32*1024*1024 f32 ]

#define NT_BATCH 32
#define CDIM     256
#define HW       1024

using short8 = __attribute__((ext_vector_type(8))) short;   // 8 bf16 (4 VGPRs)
using f32x16 = __attribute__((ext_vector_type(16))) float;  // 32x32 MFMA acc
using f32x4v = __attribute__((ext_vector_type(4))) float;

__device__ __forceinline__ unsigned pk2(float a, float b) {
  float2 t; t.x = a; t.y = b;
  __hip_bfloat162 h = __float22bfloat162_rn(t);   // v_cvt_pk_bf16_f32
  return *reinterpret_cast<unsigned*>(&h);
}
__device__ __forceinline__ void wr64(void* dst, float a, float b, float c, float d) {
  uint2 v; v.x = pk2(a, b); v.y = pk2(c, d);
  *reinterpret_cast<uint2*>(dst) = v;
}
__device__ __forceinline__ void wr128(void* dst, f32x4v p0, f32x4v p1) {
  uint4 v; v.x = pk2(p0[0], p0[1]); v.y = pk2(p0[2], p0[3]);
  v.z = pk2(p1[0], p1[1]); v.w = pk2(p1[2], p1[3]);
  *reinterpret_cast<uint4*>(dst) = v;
}

// Drains this wave's LDS ops only; VMEM (prefetch + e stores) stays in
// flight across the barrier. sched_barrier pins surroundings (rule #18).
__device__ __forceinline__ void barrier_lgkm() {
  __builtin_amdgcn_sched_barrier(0);
  asm volatile("s_waitcnt lgkmcnt(0)" ::: "memory");
  __builtin_amdgcn_s_barrier();
  __builtin_amdgcn_sched_barrier(0);
}

// Scores K-chunk region unions with the PV staging region (disjoint phases).
union SMEM {
  unsigned short As[256][72];                                    // 36864 B
  struct { unsigned short Vs[256][72]; unsigned short Ps[64][72]; } pv;  // 46080 B
};
// Qs 33792 + SMEM 46080 + csum/inv 512 = 80384 B -> 2 blocks/CU.

__global__ __launch_bounds__(512, 4) void k_fused(const float* __restrict__ Kp,
                                                  const float* __restrict__ Qp,
                                                  const float* __restrict__ Vp,
                                                  float* __restrict__ A_out,
                                                  float* __restrict__ O) {
  __shared__ __align__(16) unsigned short Qs[64][264];
  __shared__ __align__(16) SMEM sm;
  __shared__ float csum[64];
  __shared__ float inv_s[64];

  // XCD-chunked swizzle: each XCD gets 64 logical blocks (=4 nt) so a
  // batch's K/V panels stay in one L2.
  const int hbid = blockIdx.y * 16 + blockIdx.x;            // 0..511
  const int lbid = ((hbid & 7) << 6) | (hbid >> 3);         // bijective
  const int nt = lbid >> 4;
  const int q0 = (lbid & 15) << 6;

  const float* Kb = Kp + (size_t)nt * (CDIM * HW);
  const float* Qb = Qp + (size_t)nt * (CDIM * HW);
  const float* Vb = Vp + (size_t)nt * (CDIM * HW);
  float* Ab = A_out + (size_t)nt * (HW * HW);
  float* Ob = O + (size_t)nt * (CDIM * HW);

  const int t = threadIdx.x, lane = t & 63;
  const int wave = t >> 6;            // 0..7
  const int l31 = lane & 31, lhi = lane >> 5;

  if (t < 64) csum[t] = 0.f;

  // ---- shared prefetch register block (time-shared between K and V) ----
  f32x4v pf[8];
  const int kcb = (t & 15) << 2, kpp = ((t >> 4) << 2) & 255;  // K map (2 tasks)
  const int kpp2 = (((t + 512) >> 4) << 2) & 255;
  auto loadK = [&](int P0_, int C0_) {
    #pragma unroll
    for (int j = 0; j < 4; ++j) {
      pf[j]     = *(const f32x4v*)&Kb[(size_t)(C0_ + kcb + j) * HW + P0_ + kpp];
      pf[4 + j] = *(const f32x4v*)&Kb[(size_t)(C0_ + kcb + j) * HW + P0_ + kpp2];
    }
  };
  const int vc = t >> 1, vp = (t & 1) << 5;                    // V map
  auto loadV = [&](int p0_) {
    #pragma unroll
    for (int g = 0; g < 8; ++g)
      pf[g] = *(const f32x4v*)&Vb[(size_t)vc * HW + p0_ + vp + (g << 2)];
  };

  loadK(0, 0);   // first K chunk in flight under Q staging

  // ---- stage Q resident: Qs[q][c], 64q x 256c ----
  #pragma unroll
  for (int j2 = 0; j2 < 2; ++j2) {
    const int u = t + (j2 << 9);
    const int cb4 = (u & 63) << 2, qb4 = (u >> 6) << 2;
    f32x4v qv[4];
    #pragma unroll
    for (int j = 0; j < 4; ++j)
      qv[j] = *(const f32x4v*)&Qb[(size_t)(cb4 + j) * HW + q0 + qb4];
    #pragma unroll
    for (int i = 0; i < 4; ++i)
      wr64(&Qs[qb4 + i][cb4], qv[0][i], qv[1][i], qv[2][i], qv[3][i]);
  }

  float part[2] = {0.f, 0.f};
  f32x16 av[2];                        // raw V*e accumulator (pval*colsum)
  #pragma unroll
  for (int n = 0; n < 2; ++n)
    #pragma unroll
    for (int r = 0; r < 16; ++r) av[n][r] = 0.f;

  for (int pt = 0; pt < 4; ++pt) {
    const int P0 = pt << 8;
    f32x16 acc[2];                     // scores -> e (in place)
    #pragma unroll
    for (int n = 0; n < 2; ++n)
      #pragma unroll
      for (int r = 0; r < 16; ++r) acc[n][r] = 0.f;

    // -------- S phases: scores over c, 64-c chunks --------
    #pragma unroll
    for (int cc = 0; cc < 4; ++cc) {
      barrier_lgkm();   // A: prior fragment ds_reads complete (all waves)
      #pragma unroll
      for (int i = 0; i < 4; ++i) {
        wr64(&sm.As[kpp + i][kcb],  pf[0][i], pf[1][i], pf[2][i], pf[3][i]);
        wr64(&sm.As[kpp2 + i][kcb], pf[4][i], pf[5][i], pf[6][i], pf[7][i]);
      }
      if (cc < 3) loadK(P0, (cc + 1) << 6);   // in flight across barrier B
      else        loadV(P0);                  // V for P0 sub-chunk
      barrier_lgkm();   // B: As staged + visible
      __builtin_amdgcn_s_setprio(1);
      #pragma unroll
      for (int ks = 0; ks < 4; ++ks) {
        short8 a_ = *(const short8*)&sm.As[wave * 32 + l31][ks * 16 + lhi * 8];
        short8 b0 = *(const short8*)&Qs[l31][(cc << 6) + ks * 16 + lhi * 8];
        short8 b1 = *(const short8*)&Qs[32 + l31][(cc << 6) + ks * 16 + lhi * 8];
        acc[0] = __builtin_amdgcn_mfma_f32_32x32x16_bf16(a_, b0, acc[0], 0, 0, 0);
        acc[1] = __builtin_amdgcn_mfma_f32_32x32x16_bf16(a_, b1, acc[1], 0, 0, 0);
      }
      __builtin_amdgcn_s_setprio(0);
    }

    // -------- epilogue: e in-place; colsum partials; raw-e store --------
    const int rbase = wave * 32 + (lhi << 2);
    #pragma unroll
    for (int n = 0; n < 2; ++n) {
      const int col = q0 + n * 32 + l31;
      #pragma unroll
      for (int r = 0; r < 16; ++r) {
        acc[n][r] = __expf(acc[n][r] * 0.0625f);
        part[n] += acc[n][r];
        const int row = P0 + rbase + (r & 3) + ((r >> 2) << 3);
        Ab[(size_t)row * HW + col] = acc[n][r];   // raw e; tail normalizes
      }
    }

    // -------- P phases: PV over this tile's p, 64-p sub-chunks --------
    #pragma unroll
    for (int j = 0; j < 4; ++j) {
      barrier_lgkm();   // A: prior fragment ds_reads complete
      // stage Vs[256c][64p] (all threads, from pf)
      wr128(&sm.pv.Vs[vc][vp],      pf[0], pf[1]);
      wr128(&sm.pv.Vs[vc][vp + 8],  pf[2], pf[3]);
      wr128(&sm.pv.Vs[vc][vp + 16], pf[4], pf[5]);
      wr128(&sm.pv.Vs[vc][vp + 24], pf[6], pf[7]);
      // owning 2 waves stage Ps[q][p] straight from acc (e) registers
      if ((wave >> 1) == j) {
        const int pbase = (wave & 1) * 32 + (lhi << 2);
        #pragma unroll
        for (int n = 0; n < 2; ++n)
          #pragma unroll
          for (int g = 0; g < 4; ++g)
            wr64(&sm.pv.Ps[n * 32 + l31][pbase + (g << 3)],
                 acc[n][4 * g], acc[n][4 * g + 1],
                 acc[n][4 * g + 2], acc[n][4 * g + 3]);
      }
      if (j < 3)      loadV(P0 + ((j + 1) << 6));   // in flight across B
      else if (pt < 3) loadK(P0 + 256, 0);
      barrier_lgkm();   // B: Vs/Ps staged + visible
      __builtin_amdgcn_s_setprio(1);
      #pragma unroll
      for (int kk = 0; kk < 4; ++kk) {
        short8 a_ = *(const short8*)&sm.pv.Vs[wave * 32 + l31][kk * 16 + lhi * 8];
        short8 b0 = *(const short8*)&sm.pv.Ps[l31][kk * 16 + lhi * 8];
        short8 b1 = *(const short8*)&sm.pv.Ps[32 + l31][kk * 16 + lhi * 8];
        av[0] = __builtin_amdgcn_mfma_f32_32x32x16_bf16(a_, b0, av[0], 0, 0, 0);
        av[1] = __builtin_amdgcn_mfma_f32_32x32x16_bf16(a_, b1, av[1], 0, 0, 0);
      }
      __builtin_amdgcn_s_setprio(0);
    }
  }

  // ---- colsum reduce -> inv; FULL syncthreads drains e stores (vmcnt) ----
  atomicAdd(&csum[l31], part[0]);
  atomicAdd(&csum[32 + l31], part[1]);
  __syncthreads();
  if (t < 64) inv_s[t] = 1.0f / csum[t];
  __syncthreads();

  // ---- pval epilogue: apply inv post-accumulation ----
  #pragma unroll
  for (int n = 0; n < 2; ++n) {
    const int col = q0 + n * 32 + l31;
    const float invc = inv_s[n * 32 + l31];
    const int cbase = wave * 32 + (lhi << 2);
    #pragma unroll
    for (int r = 0; r < 16; ++r) {
      const int c = cbase + (r & 3) + ((r >> 2) << 3);
      Ob[(size_t)c * HW + col] = av[n][r] * invc;
    }
  }

  // ---- streaming tail: normalize own attn strip in place (no barriers) ----
  const int trow = t >> 4;             // 0..31
  const int sq = (t & 15) << 2;        // 4 q columns
  const f32x4v inv4 = *(const f32x4v*)&inv_s[sq];
  for (int s = 0; s < 32; s += 8) {
    f32x4v er[8];
    #pragma unroll
    for (int u = 0; u < 8; ++u)
      er[u] = *(const f32x4v*)&Ab[(size_t)(((s + u) << 5) + trow) * HW + q0 + sq];
    #pragma unroll
    for (int u = 0; u < 8; ++u)
      *(f32x4v*)&Ab[(size_t)(((s + u) << 5) + trow) * HW + q0 + sq] = er[u] * inv4;
  }
}

// ---------------------------------------------------------------------------
extern "C" void kernel_launch(void* const* d_in, const int* in_sizes, int n_in,
                              void* d_out, int out_size, void* d_ws, size_t ws_size,
                              hipStream_t stream) {
  const float* key   = (const float*)d_in[0];
  const float* query = (const float*)d_in[1];
  const float* value = (const float*)d_in[2];
  float* out  = (float*)d_out;
  float* pval = out;
  float* attn = out + (size_t)NT_BATCH * CDIM * HW;

  k_fused<<<dim3(16, NT_BATCH), 512, 0, stream>>>(key, query, value, attn, pval);
}

// Round 6
// 404.092 us; speedup vs baseline: 1.1450x; 1.1450x over previous
//
#include <hip/hip_runtime.h>
#include <hip/hip_bf16.h>

// N=4, T=8 -> NT=32 batches; C=C2=256; H*W=1024.
// ONE kernel. Block = (nt, 64-q strip), 512 threads (8 waves), 1 block/CU.
//
// e NEVER leaves registers: the block owns all 1024 p for its 64 q, and the
// whole e-strip in bf16-pair form is 64 VGPRs/thread (epair[4][2][4] uint2).
//   Pass (per 256-p tile x4): scores MFMA -> e = exp(s/16) -> pk2 to epair;
//     colsum partials in regs; PV MFMA fused right after, Ps staged from
//     epair (raw e; pval = inv * sum V*e applied at the end).
//   Tail: attn = bf16(e)*inv -- PURE WRITE from registers (no global read).
// Traffic ~ compulsory floor: read K/Q/V ~100 MB, write attn+pval ~168 MB.
//
// Double-buffered LDS (126 KB, 1 block/CU): one lgkm-only barrier per phase
// (32 total). Parity aliasing As[b] == Vs[b] is safe: buffer b's readers
// finished before the next phase's barrier, and b is rewritten 2 phases
// later. Prefetch depth-2: pfA/pfB loaded at phase i, consumed at i+2.
// d_out = [ p_val : 32*256*1024 f32 ][ attn : 32*1024*1024 f32 ]

#define NT_BATCH 32
#define CDIM     256
#define HW       1024

using short8 = __attribute__((ext_vector_type(8))) short;   // 8 bf16 (4 VGPRs)
using f32x16 = __attribute__((ext_vector_type(16))) float;  // 32x32 MFMA acc
using f32x4v = __attribute__((ext_vector_type(4))) float;

__device__ __forceinline__ unsigned pk2(float a, float b) {
  float2 t; t.x = a; t.y = b;
  __hip_bfloat162 h = __float22bfloat162_rn(t);   // v_cvt_pk_bf16_f32
  return *reinterpret_cast<unsigned*>(&h);
}
__device__ __forceinline__ void wr64(void* dst, float a, float b, float c, float d) {
  uint2 v; v.x = pk2(a, b); v.y = pk2(c, d);
  *reinterpret_cast<uint2*>(dst) = v;
}
__device__ __forceinline__ void wr128(void* dst, f32x4v p0, f32x4v p1) {
  uint4 v; v.x = pk2(p0[0], p0[1]); v.y = pk2(p0[2], p0[3]);
  v.z = pk2(p1[0], p1[1]); v.w = pk2(p1[2], p1[3]);
  *reinterpret_cast<uint4*>(dst) = v;
}

// Drains this wave's LDS ops only; VMEM prefetch stays in flight across the
// barrier. sched_barrier pins surroundings (rule #18).
__device__ __forceinline__ void barrier_lgkm() {
  __builtin_amdgcn_sched_barrier(0);
  asm volatile("s_waitcnt lgkmcnt(0)" ::: "memory");
  __builtin_amdgcn_s_barrier();
  __builtin_amdgcn_sched_barrier(0);
}

// Double-buffered staging; As[b] aliases Vs[b] by parity (see header).
union SMEM {
  unsigned short As[2][256][72];                                   // 73728 B
  struct { unsigned short Vs[2][256][72]; unsigned short Ps[2][64][72]; } b;  // 92160 B
};
// Qs 33792 + SMEM 92160 + csum/inv 512 = 126464 B -> 1 block/CU, 8 waves.

__global__ __launch_bounds__(512, 2) void k_fused(const float* __restrict__ Kp,
                                                  const float* __restrict__ Qp,
                                                  const float* __restrict__ Vp,
                                                  float* __restrict__ A_out,
                                                  float* __restrict__ O) {
  __shared__ __align__(16) unsigned short Qs[64][264];
  __shared__ __align__(16) SMEM sm;
  __shared__ float csum[64];
  __shared__ float inv_s[64];

  // XCD-chunked swizzle: each XCD gets a contiguous chunk of logical blocks
  // (=2 nt co-resident) so a batch's K/V panels stay in one L2.
  const int hbid = blockIdx.y * 16 + blockIdx.x;            // 0..511
  const int lbid = ((hbid & 7) << 6) | (hbid >> 3);         // bijective
  const int nt = lbid >> 4;
  const int q0 = (lbid & 15) << 6;

  const float* Kb = Kp + (size_t)nt * (CDIM * HW);
  const float* Qb = Qp + (size_t)nt * (CDIM * HW);
  const float* Vb = Vp + (size_t)nt * (CDIM * HW);
  float* Ab = A_out + (size_t)nt * (HW * HW);
  float* Ob = O + (size_t)nt * (CDIM * HW);

  const int t = threadIdx.x, lane = t & 63;
  const int wave = t >> 6;            // 0..7
  const int l31 = lane & 31, lhi = lane >> 5;

  // staging maps
  const int kcb = (t & 15) << 2;                 // K: 4 c per thread
  const int kpp = ((t >> 4) << 2) & 255;         //    4 p rows, group 0
  const int kpp2 = kpp + 128;                    //    group 1
  const int vc = t >> 1, vp = (t & 1) << 5;      // V: c-row, 32-p half

  f32x4v pfA[8], pfB[8];
  auto issueK = [&](f32x4v (&pf_)[8], int P0_, int C0_) {
    #pragma unroll
    for (int j = 0; j < 4; ++j) {
      pf_[j]     = *(const f32x4v*)&Kb[(size_t)(C0_ + kcb + j) * HW + P0_ + kpp];
      pf_[4 + j] = *(const f32x4v*)&Kb[(size_t)(C0_ + kcb + j) * HW + P0_ + kpp2];
    }
  };
  auto issueV = [&](f32x4v (&pf_)[8], int p0_) {
    #pragma unroll
    for (int g = 0; g < 8; ++g)
      pf_[g] = *(const f32x4v*)&Vb[(size_t)vc * HW + p0_ + vp + (g << 2)];
  };

  issueK(pfA, 0, 0);     // consumed at S0 of tile 0
  issueK(pfB, 0, 64);    // consumed at S1 of tile 0

  if (t < 64) csum[t] = 0.f;

  // ---- stage Q resident: Qs[q][c], 64q x 256c ----
  #pragma unroll
  for (int j2 = 0; j2 < 2; ++j2) {
    const int u = t + (j2 << 9);
    const int cb4 = (u & 63) << 2, qb4 = (u >> 6) << 2;
    f32x4v qv[4];
    #pragma unroll
    for (int j = 0; j < 4; ++j)
      qv[j] = *(const f32x4v*)&Qb[(size_t)(cb4 + j) * HW + q0 + qb4];
    #pragma unroll
    for (int i = 0; i < 4; ++i)
      wr64(&Qs[qb4 + i][cb4], qv[0][i], qv[1][i], qv[2][i], qv[3][i]);
  }

  uint2 epair[4][2][4];                // whole e-strip, bf16 pairs (64 VGPR)
  float part[2] = {0.f, 0.f};
  f32x16 acc[2];                       // scores -> e (per tile)
  f32x16 av[2];                        // raw V*e accumulator
  #pragma unroll
  for (int n = 0; n < 2; ++n)
    #pragma unroll
    for (int r = 0; r < 16; ++r) av[n][r] = 0.f;

  // S phase: stage As[par] from pf, issue depth-2 refill, barrier, 8 MFMA.
  auto sphase = [&](int par, f32x4v (&pf_)[8], int P0_, int cc) {
    #pragma unroll
    for (int i = 0; i < 4; ++i) {
      wr64(&sm.As[par][kpp + i][kcb],  pf_[0][i], pf_[1][i], pf_[2][i], pf_[3][i]);
      wr64(&sm.As[par][kpp2 + i][kcb], pf_[4][i], pf_[5][i], pf_[6][i], pf_[7][i]);
    }
    if (cc < 2) issueK(pf_, P0_, (cc + 2) << 6);        // consumed S(cc+2)
    else        issueV(pf_, P0_ + ((cc - 2) << 6));     // consumed P(cc-2)
    barrier_lgkm();
    __builtin_amdgcn_s_setprio(1);
    #pragma unroll
    for (int ks = 0; ks < 4; ++ks) {
      short8 a_ = *(const short8*)&sm.As[par][wave * 32 + l31][ks * 16 + lhi * 8];
      short8 b0 = *(const short8*)&Qs[l31][(cc << 6) + ks * 16 + lhi * 8];
      short8 b1 = *(const short8*)&Qs[32 + l31][(cc << 6) + ks * 16 + lhi * 8];
      acc[0] = __builtin_amdgcn_mfma_f32_32x32x16_bf16(a_, b0, acc[0], 0, 0, 0);
      acc[1] = __builtin_amdgcn_mfma_f32_32x32x16_bf16(a_, b1, acc[1], 0, 0, 0);
    }
    __builtin_amdgcn_s_setprio(0);
  };

  // P phase: stage Vs[par] from pf + Ps[par] from epair, refill, barrier, PV.
  auto pphase = [&](int par, f32x4v (&pf_)[8], int P0_, int j, int pt_) {
    wr128(&sm.b.Vs[par][vc][vp],      pf_[0], pf_[1]);
    wr128(&sm.b.Vs[par][vc][vp + 8],  pf_[2], pf_[3]);
    wr128(&sm.b.Vs[par][vc][vp + 16], pf_[4], pf_[5]);
    wr128(&sm.b.Vs[par][vc][vp + 24], pf_[6], pf_[7]);
    if ((wave >> 1) == j) {
      const int pbase = (wave & 1) * 32 + (lhi << 2);
      #pragma unroll
      for (int n = 0; n < 2; ++n)
        #pragma unroll
        for (int g = 0; g < 4; ++g)
          *reinterpret_cast<uint2*>(&sm.b.Ps[par][n * 32 + l31][pbase + (g << 3)]) =
              epair[pt_][n][g];
    }
    if (j < 2)       issueV(pf_, P0_ + ((j + 2) << 6));     // consumed P(j+2)
    else if (pt_ < 3) issueK(pf_, P0_ + 256, (j - 2) << 6); // next tile S(j-2)
    barrier_lgkm();
    __builtin_amdgcn_s_setprio(1);
    #pragma unroll
    for (int kk = 0; kk < 4; ++kk) {
      short8 a_ = *(const short8*)&sm.b.Vs[par][wave * 32 + l31][kk * 16 + lhi * 8];
      short8 b0 = *(const short8*)&sm.b.Ps[par][l31][kk * 16 + lhi * 8];
      short8 b1 = *(const short8*)&sm.b.Ps[par][32 + l31][kk * 16 + lhi * 8];
      av[0] = __builtin_amdgcn_mfma_f32_32x32x16_bf16(a_, b0, av[0], 0, 0, 0);
      av[1] = __builtin_amdgcn_mfma_f32_32x32x16_bf16(a_, b1, av[1], 0, 0, 0);
    }
    __builtin_amdgcn_s_setprio(0);
  };

  #pragma unroll
  for (int pt = 0; pt < 4; ++pt) {
    const int P0 = pt << 8;
    #pragma unroll
    for (int n = 0; n < 2; ++n)
      #pragma unroll
      for (int r = 0; r < 16; ++r) acc[n][r] = 0.f;

    sphase(0, pfA, P0, 0);
    sphase(1, pfB, P0, 1);
    sphase(0, pfA, P0, 2);
    sphase(1, pfB, P0, 3);

    // epilogue: e = exp(s/16); colsum partials; pack to epair (registers)
    #pragma unroll
    for (int n = 0; n < 2; ++n) {
      #pragma unroll
      for (int r = 0; r < 16; ++r) {
        acc[n][r] = __expf(acc[n][r] * 0.0625f);
        part[n] += acc[n][r];
      }
      #pragma unroll
      for (int g = 0; g < 4; ++g) {
        epair[pt][n][g].x = pk2(acc[n][4 * g],     acc[n][4 * g + 1]);
        epair[pt][n][g].y = pk2(acc[n][4 * g + 2], acc[n][4 * g + 3]);
      }
    }

    pphase(0, pfA, P0, 0, pt);
    pphase(1, pfB, P0, 1, pt);
    pphase(0, pfA, P0, 2, pt);
    pphase(1, pfB, P0, 3, pt);
  }

  // ---- colsum reduce -> inv ----
  atomicAdd(&csum[l31], part[0]);
  atomicAdd(&csum[32 + l31], part[1]);
  __syncthreads();
  if (t < 64) inv_s[t] = 1.0f / csum[t];
  __syncthreads();

  // ---- pval epilogue: apply inv post-accumulation ----
  #pragma unroll
  for (int n = 0; n < 2; ++n) {
    const int col = q0 + n * 32 + l31;
    const float invc = inv_s[n * 32 + l31];
    const int cbase = wave * 32 + (lhi << 2);
    #pragma unroll
    for (int r = 0; r < 16; ++r) {
      const int c = cbase + (r & 3) + ((r >> 2) << 3);
      Ob[(size_t)c * HW + col] = av[n][r] * invc;
    }
  }

  // ---- attn tail: PURE WRITE from registers (attn = bf16(e) * inv) ----
  #pragma unroll
  for (int n = 0; n < 2; ++n) {
    const int col = q0 + n * 32 + l31;
    const float invc = inv_s[n * 32 + l31];
    #pragma unroll
    for (int pt = 0; pt < 4; ++pt) {
      const int rb = (pt << 8) + wave * 32 + (lhi << 2);
      #pragma unroll
      for (int g = 0; g < 4; ++g) {
        const uint2 u = epair[pt][n][g];
        Ab[(size_t)(rb + 8 * g + 0) * HW + col] = __uint_as_float(u.x << 16) * invc;
        Ab[(size_t)(rb + 8 * g + 1) * HW + col] = __uint_as_float(u.x & 0xffff0000u) * invc;
        Ab[(size_t)(rb + 8 * g + 2) * HW + col] = __uint_as_float(u.y << 16) * invc;
        Ab[(size_t)(rb + 8 * g + 3) * HW + col] = __uint_as_float(u.y & 0xffff0000u) * invc;
      }
    }
  }
}

// ---------------------------------------------------------------------------
extern "C" void kernel_launch(void* const* d_in, const int* in_sizes, int n_in,
                              void* d_out, int out_size, void* d_ws, size_t ws_size,
                              hipStream_t stream) {
  const float* key   = (const float*)d_in[0];
  const float* query = (const float*)d_in[1];
  const float* value = (const float*)d_in[2];
  float* out  = (float*)d_out;
  float* pval = out;
  float* attn = out + (size_t)NT_BATCH * CDIM * HW;

  k_fused<<<dim3(16, NT_BATCH), 512, 0, stream>>>(key, query, value, attn, pval);
}